// Round 3
// baseline (501.732 us; speedup 1.0000x reference)
//
#include <hip/hip_runtime.h>
#include <stdint.h>

// Problem: B=32, T=128, C=64, DIN=DOUT=32, 4 gates. All-fp32 VALU design:
// weights stream global->VGPR (no reuse exists for them within a WG), only
// x_t/h (tiny, shared) go through LDS. 256 WGs = q(0..3)*64 + c -> all CUs
// busy; the 4x weight re-read is served by the per-XCD L2 (copies of channel
// c land on XCD c%8 together), HBM-unique traffic stays 288 MB.
#define T_STEPS 128
#define C_CH    64
#define SROW    72   // S row stride (floats): 64 data + 8 pad -> 2-way max
#define EROW    10   // exch row stride (floats)

// Barrier draining only LDS (lgkmcnt): weight/x prefetch loads stay in
// flight across the per-step barriers (no vmcnt(0) drain).
__device__ __forceinline__ void lds_barrier() {
  asm volatile("s_waitcnt lgkmcnt(0)\n\ts_barrier" ::: "memory");
}

__device__ __forceinline__ float fast_sigmoid(float v) {
  return __builtin_amdgcn_rcpf(1.0f + __expf(-v));
}
__device__ __forceinline__ float fast_tanh(float v) {
  return fmaf(2.0f, __builtin_amdgcn_rcpf(1.0f + __expf(-2.0f * v)), -1.0f);
}

// Block: 256 threads = (g:4 gates) x (iq:16 row-pairs i,i+16) x (kq:4
// K-quarters of 16). kq 0,1 -> xOps j 0:16/16:32; kq 2,3 -> hOps j 0:16/16:32.
// S plane columns kq*16 index the [x_t ; h] concat directly.
__global__ void __launch_bounds__(256, 1)
lstm_kernel(const float* __restrict__ x, const float* __restrict__ xOps,
            const float* __restrict__ hOps, float* __restrict__ out) {
  __shared__ float S[8 * SROW];       // [b][0:32]=x_t, [32:64]=h
  __shared__ float exch[128 * EROW];  // [(g*32+i)][b] gate pre-activations

  const int tid = threadIdx.x;
  const int c   = blockIdx.x & 63;
  const int q   = blockIdx.x >> 6;

  const int kq = tid & 3;
  const int iq = (tid >> 2) & 15;
  const int g  = tid >> 6;

  // zero the h region only (x region is staged fresh each step; zeroing it
  // too would be a write-write race with the t=0 staging below)
  S[(tid >> 5) * SROW + 32 + (tid & 31)] = 0.0f;

  // weight row pointers (t-invariant part)
  const float* wbase = (kq < 2) ? xOps : hOps;
  const int    jo    = (kq & 1) * 16;
  const float* wp0 = wbase + ((size_t)g * T_STEPS * C_CH + c) * 1024 + iq * 32 + jo;
  const float* wp1 = wp0 + 512;                 // row iq+16
  const size_t WT  = (size_t)C_CH * 1024;       // per-t weight stride

  // x staging: 64 threads, float4 each: b=tid>>3, j=(tid&7)*4
  const int bx = tid >> 3, jx = (tid & 7) * 4;
  const float* xp = x + (size_t)(q * 8 + bx) * (T_STEPS * C_CH * 32) + c * 32 + jx;
  const size_t XT = (size_t)C_CH * 32;          // per-t x stride

  const int eb = tid >> 5;   // elementwise: local batch 0..7
  const int ei = tid & 31;   // elementwise: output dim

  auto loadw = [&](float4 w0[4], float4 w1[4], int t) {
#pragma unroll
    for (int it = 0; it < 4; ++it) {
      w0[it] = *(const float4*)(wp0 + (size_t)t * WT + it * 4);
      w1[it] = *(const float4*)(wp1 + (size_t)t * WT + it * 4);
    }
  };

  // depth-2 prefetch: wa = t, wb = t+1; reload each right after consumption.
  float4 wa0[4], wa1[4], wb0[4], wb1[4];
  float4 xa = make_float4(0.f, 0.f, 0.f, 0.f), xb = xa;
  loadw(wa0, wa1, 0);
  loadw(wb0, wb1, 1);
  if (tid < 64) { xa = *(const float4*)xp; xb = *(const float4*)(xp + XT); }

  float cs = 0.0f;  // cell state for (eb, ei), persistent in-register

  auto step = [&](int t, float4 w0[4], float4 w1[4], float4& xv) {
    if (tid < 64) *(float4*)&S[bx * SROW + jx] = xv;
    lds_barrier();  // x stage + prev h writes visible

    float acc0[8], acc1[8];
#pragma unroll
    for (int b = 0; b < 8; ++b) { acc0[b] = 0.f; acc1[b] = 0.f; }
#pragma unroll
    for (int it = 0; it < 4; ++it) {
#pragma unroll
      for (int b = 0; b < 8; ++b) {
        float4 sv = *(const float4*)&S[b * SROW + kq * 16 + it * 4];
        acc0[b] = fmaf(w0[it].x, sv.x, acc0[b]);
        acc0[b] = fmaf(w0[it].y, sv.y, acc0[b]);
        acc0[b] = fmaf(w0[it].z, sv.z, acc0[b]);
        acc0[b] = fmaf(w0[it].w, sv.w, acc0[b]);
        acc1[b] = fmaf(w1[it].x, sv.x, acc1[b]);
        acc1[b] = fmaf(w1[it].y, sv.y, acc1[b]);
        acc1[b] = fmaf(w1[it].z, sv.z, acc1[b]);
        acc1[b] = fmaf(w1[it].w, sv.w, acc1[b]);
      }
    }

    // prefetch t+2 into the buffer just consumed; flies through step t+1
    if (t + 2 < T_STEPS) {
      loadw(w0, w1, t + 2);
      if (tid < 64) xv = *(const float4*)(xp + (size_t)(t + 2) * XT);
    }

    // combine K-quarters across kq lanes (lane^1, lane^2)
#pragma unroll
    for (int b = 0; b < 8; ++b) {
      acc0[b] += __shfl_xor(acc0[b], 1, 64);
      acc0[b] += __shfl_xor(acc0[b], 2, 64);
      acc1[b] += __shfl_xor(acc1[b], 1, 64);
      acc1[b] += __shfl_xor(acc1[b], 2, 64);
    }
    // each kq lane publishes its 2 batches
    {
      const int b0 = kq * 2;
      *(float2*)&exch[(g * 32 + iq) * EROW + b0]      = make_float2(acc0[b0], acc0[b0 + 1]);
      *(float2*)&exch[(g * 32 + 16 + iq) * EROW + b0] = make_float2(acc1[b0], acc1[b0 + 1]);
    }
    lds_barrier();  // exch visible

    // elementwise cell update: thread (eb, ei)
    {
      float X0 = exch[(0 * 32 + ei) * EROW + eb];
      float X1 = exch[(1 * 32 + ei) * EROW + eb];
      float X2 = exch[(2 * 32 + ei) * EROW + eb];
      float X3 = exch[(3 * 32 + ei) * EROW + eb];
      float ig = fast_sigmoid(X0);
      float fg = fast_sigmoid(X1);
      float gg = fast_tanh(X2);
      float og = fast_sigmoid(X3);
      cs = fg * cs + ig * gg;
      float hval = og * fast_tanh(cs);
      if (t == T_STEPS - 1) {
        out[((size_t)(q * 8 + eb) * C_CH + c) * 32 + ei] = hval;
      } else {
        S[eb * SROW + 32 + ei] = hval;   // visible at next step's barrier A
      }
    }
  };

#pragma unroll 1
  for (int t = 0; t < T_STEPS; t += 2) {
    step(t,     wa0, wa1, xa);
    step(t + 1, wb0, wb1, xb);
  }
}

extern "C" void kernel_launch(void* const* d_in, const int* in_sizes, int n_in,
                              void* d_out, int out_size, void* d_ws, size_t ws_size,
                              hipStream_t stream) {
  const float* x    = (const float*)d_in[0];
  const float* xOps = (const float*)d_in[1];
  const float* hOps = (const float*)d_in[2];
  lstm_kernel<<<dim3(256), dim3(256), 0, stream>>>(x, xOps, hOps, (float*)d_out);
}